// Round 4
// baseline (4637.449 us; speedup 1.0000x reference)
//
#include <hip/hip_runtime.h>
#include <math.h>

namespace {
constexpr int kB = 2, kT = 1024, kE = 768, kH = 12, kL = 4, kV = 50257;
constexpr int kHD = 64;
constexpr int kM = kB * kT;    // 2048 rows
constexpr int kFF = 4 * kE;    // 3072
constexpr int kQS = 3 * kE;    // fused qkv row stride (2304)
constexpr int kVP = 50304;     // head W padded cols (mult of 128 and 64)
constexpr float kEPS = 1e-3f;
constexpr float kSCALE = 0.03608439182435161f;  // 768^-0.5 (reference scales by E, not HD)
}

typedef __bf16 bf16x8 __attribute__((ext_vector_type(8)));
typedef float f32x4 __attribute__((ext_vector_type(4)));
typedef unsigned short u16;

// Split fp32 into hi/lo bf16 (as top-16-bit patterns). x == hi + lo + O(2^-17 x).
__device__ __forceinline__ void split_f(float x, unsigned &hb, unsigned &lb) {
  unsigned xb = __float_as_uint(x);
  hb = xb & 0xFFFF0000u;
  lb = __float_as_uint(x - __uint_as_float(hb)) & 0xFFFF0000u;
}
// pack two top-bit bf16 patterns into one u32 (b0 -> low half, b1 -> high half)
__device__ __forceinline__ unsigned pk(unsigned b0, unsigned b1) {
  return (b0 >> 16) | b1;
}

// x[b,t,:] = tok_emb[tokens[b,t],:] + pos_emb[t,:]
__global__ __launch_bounds__(256) void embed_kernel(
    const int* __restrict__ tokens, const float* __restrict__ tok_emb,
    const float* __restrict__ pos_emb, float* __restrict__ x) {
  int gid = blockIdx.x * 256 + threadIdx.x;  // over kM*kE/4
  int m = gid / (kE / 4);
  int c = gid % (kE / 4);
  int t = m % kT;
  int tok = tokens[m];
  float4 a = ((const float4*)tok_emb)[(size_t)tok * (kE / 4) + c];
  float4 b = ((const float4*)pos_emb)[(size_t)t * (kE / 4) + c];
  ((float4*)x)[gid] = make_float4(a.x + b.x, a.y + b.y, a.z + b.z, a.w + b.w);
}

// LayerNorm; writes optional f32 out + bf16 hi/lo split (GEMM A-operand format).
__global__ __launch_bounds__(256) void ln_kernel(
    const float* __restrict__ x, const float* __restrict__ g,
    const float* __restrict__ bta, float* __restrict__ outf,
    u16* __restrict__ outh, u16* __restrict__ outl) {
  __shared__ float ssum[256], ssq[256];
  int row = blockIdx.x, tid = threadIdx.x;
  const float* xr = x + (size_t)row * kE;
  float v0 = xr[tid], v1 = xr[tid + 256], v2 = xr[tid + 512];
  ssum[tid] = v0 + v1 + v2;
  ssq[tid] = v0 * v0 + v1 * v1 + v2 * v2;
  __syncthreads();
  for (int off = 128; off > 0; off >>= 1) {
    if (tid < off) { ssum[tid] += ssum[tid + off]; ssq[tid] += ssq[tid + off]; }
    __syncthreads();
  }
  float mu = ssum[0] * (1.f / kE);
  float var = ssq[0] * (1.f / kE) - mu * mu;
  float rstd = rsqrtf(var + kEPS);
  size_t rb = (size_t)row * kE;
#pragma unroll
  for (int p = 0; p < 3; ++p) {
    int c = tid + p * 256;
    float v = (p == 0) ? v0 : (p == 1) ? v1 : v2;
    float y = (v - mu) * rstd * g[c] + bta[c];
    if (outf) outf[rb + c] = y;
    unsigned hb, lb;
    split_f(y, hb, lb);
    outh[rb + c] = (u16)(hb >> 16);
    outl[rb + c] = (u16)(lb >> 16);
  }
}

// Weight conversion body: f32 [K][Nsrc] tile -> k8-tiled bf16 hi/lo:
// elem (k,n) at ((k>>3)*Ndt + colOff + n)*8 + (k&7). Zero-fills n>=Nsrc.
template <int WRITE_LO>
__device__ __forceinline__ void wconv_body(
    const float* __restrict__ src, u16* __restrict__ dh, u16* __restrict__ dl,
    int Nsrc, int Ndt, int colOff, int nt, int kt) {
  __shared__ float T[64][68];
  int tid = threadIdx.x;
  int cb = tid & 15, rb = tid >> 4;
#pragma unroll
  for (int p = 0; p < 4; ++p) {
    int r = p * 16 + rb;
    const float* srow = src + (size_t)(kt * 64 + r) * Nsrc;
#pragma unroll
    for (int j = 0; j < 4; ++j) {
      int n = nt * 64 + cb * 4 + j;
      T[r][cb * 4 + j] = (n < Nsrc) ? srow[n] : 0.f;
    }
  }
  __syncthreads();
#pragma unroll
  for (int q = 0; q < 2; ++q) {
    int c = tid + q * 256;
    int gg = c >> 6, n = c & 63;
    unsigned hh[8], ll[8];
#pragma unroll
    for (int j = 0; j < 8; ++j) split_f(T[gg * 8 + j][n], hh[j], ll[j]);
    size_t o = ((size_t)(kt * 8 + gg) * Ndt + (colOff + nt * 64 + n)) * 8;
    *(uint4*)&dh[o] = make_uint4(pk(hh[0], hh[1]), pk(hh[2], hh[3]),
                                 pk(hh[4], hh[5]), pk(hh[6], hh[7]));
    if (WRITE_LO)
      *(uint4*)&dl[o] = make_uint4(pk(ll[0], ll[1]), pk(ll[2], ll[3]),
                                   pk(ll[4], ll[5]), pk(ll[6], ll[7]));
  }
}

// Generic single-tensor wconv (used for the head).
template <int WRITE_LO>
__global__ __launch_bounds__(256) void wconv_kernel(
    const float* __restrict__ src, u16* __restrict__ dh, u16* __restrict__ dl,
    int Nsrc, int Ndt, int colOff) {
  wconv_body<WRITE_LO>(src, dh, dl, Nsrc, Ndt, colOff, blockIdx.x, blockIdx.y);
}

// Batched: 4 E x E tensors (wq,wk,wv -> qkv layout; wo -> own). grid (12,12,4).
struct WcArgs4 {
  const float* src[4];
  u16* dh[4];
  u16* dl[4];
  int colOff[4];
  int Ndt[4];
};
__global__ __launch_bounds__(256) void wconv_qkvo_kernel(WcArgs4 a) {
  int z = blockIdx.z;
  wconv_body<1>(a.src[z], a.dh[z], a.dl[z], kE, a.Ndt[z], a.colOff[z],
                blockIdx.x, blockIdx.y);
}

// Batched: ff1 (768x3072) at z=0, ff2 (3072x768) at z=1. grid (48,12,2).
struct WcArgsFF {
  const float* s1; u16* d1h; u16* d1l;
  const float* s2; u16* d2h; u16* d2l;
};
__global__ __launch_bounds__(256) void wconv_ff_kernel(WcArgsFF a) {
  if (blockIdx.z == 0)
    wconv_body<1>(a.s1, a.d1h, a.d1l, kFF, kFF, 0, blockIdx.x, blockIdx.y);
  else
    wconv_body<1>(a.s2, a.d2h, a.d2l, kE, kE, 0, blockIdx.y, blockIdx.x);
}

// Split-bf16 MFMA GEMM, pre-split operands (no VALU conversion in-loop).
// A: [M][K] u16 hi/lo (k-contiguous).  W: k8-tiled [K/8][Ndt][8] u16 hi(/lo).
// TERMS=3: AhWh+AlWh+AhWl; TERMS=2: AhWh+AlWh (W hi only).
// Grid: 1-D, group-swizzled. Supertile = GW N-panels x all M-tiles; within a
// group blocks run n-fast (adjacent column writes back-to-back -> L2 write
// merge), then m (group's W slice stays L2-resident; A-panel read once per m).
// Block: BN=128, BM=WMF*32, 4 waves 2x2; BK=32 per step.
// LDS rows 80B: all b128 reads/writes spread 8 lanes/16B-window (floor).
// CONTIG=1 (head): epilogue staged through LDS, stores 64-lane-contiguous
// 256B spans per instruction (scalar dwords; odd N forbids float4).
template <int WMF, int TERMS, int RELU, int OSPLIT, int CONTIG>
__global__ __launch_bounds__(256) void gemm_bf16s_kernel(
    const u16* __restrict__ Ah, const u16* __restrict__ Al,
    const u16* __restrict__ Wh, const u16* __restrict__ Wl,
    const float* __restrict__ bias, const float* __restrict__ addsrc,
    float* __restrict__ C, u16* __restrict__ Ch, u16* __restrict__ Cl,
    int N, int K, int Ndt) {
  constexpr int BM = WMF * 32;
  constexpr int AC = WMF / 2;  // uint4 A-chunks per thread (per hi|lo)
  constexpr int ABYTES = BM * 80;          // one A LDS array (u16 [BM][40])
  constexpr int WBYTES = 128 * 80;
  constexpr int STAGE = 2 * ABYTES + WBYTES + (TERMS == 3 ? WBYTES : 0);
  constexpr int CBYTES = CONTIG ? 64 * 132 * 4 : 0;
  constexpr int SBYTES = STAGE > CBYTES ? STAGE : CBYTES;
  __shared__ __align__(16) char smem[SBYTES];
  u16 (*Ash)[40] = (u16(*)[40])smem;
  u16 (*Asl)[40] = (u16(*)[40])(smem + ABYTES);
  u16 (*Wsh)[40] = (u16(*)[40])(smem + 2 * ABYTES);
  u16 (*Wsl)[40] = (u16(*)[40])(smem + 2 * ABYTES + WBYTES);  // TERMS==3 only
  float (*Cs)[132] = (float(*)[132])smem;                      // CONTIG only

  const int tid = threadIdx.x;
  const int lane = tid & 63;
  const int w = tid >> 6;
  const int wm = (w >> 1) * (WMF * 16);
  const int wn = (w & 1) * 64;
  // ---- group swizzle: n-fast within GW-panel group, then m, then group ----
  constexpr int GW = 8;
  const int NT = Ndt >> 7;              // N-tiles (Ndt multiple of 128)
  const int MT = (int)gridDim.x / NT;   // M-tiles
  int mt, nt;
  {
    int L = blockIdx.x;
    int nfull = NT / GW;
    int T = MT * GW;
    int F = nfull * T;
    if (L < F) {
      int g = L / T, r = L % T;
      mt = r / GW; nt = g * GW + (r % GW);
    } else {
      int rem = NT - nfull * GW;
      int r = L - F;
      mt = r / rem; nt = nfull * GW + (r % rem);
    }
  }
  const int m0 = mt * BM, n0 = nt * 128;
  const int fr = lane & 15, fg = lane >> 4;
  const int wn_l = tid & 127;        // W stage: this thread's n-column
  const int wk8 = (tid >> 7) * 2;    // W stage: k8-group base

  f32x4 acc[WMF][4];
#pragma unroll
  for (int i = 0; i < WMF; ++i)
#pragma unroll
    for (int j = 0; j < 4; ++j) acc[i][j] = f32x4{0.f, 0.f, 0.f, 0.f};

  uint4 aPh[AC], aPl[AC], wPh[2], wPl[2];
  (void)wPl;

#define LOAD_TILE(k0_)                                                        \
  {                                                                           \
    _Pragma("unroll") for (int q = 0; q < AC; ++q) {                          \
      int e = tid + q * 256;                                                  \
      int m = e >> 2, kq = e & 3;                                             \
      size_t off = (size_t)(m0 + m) * K + (k0_) + kq * 8;                     \
      aPh[q] = *(const uint4*)&Ah[off];                                       \
      aPl[q] = *(const uint4*)&Al[off];                                       \
    }                                                                         \
    _Pragma("unroll") for (int u = 0; u < 2; ++u) {                           \
      size_t off = ((size_t)((k0_) / 8 + wk8 + u) * Ndt + (n0 + wn_l)) * 8;   \
      wPh[u] = *(const uint4*)&Wh[off];                                       \
      if (TERMS == 3) wPl[u] = *(const uint4*)&Wl[off];                       \
    }                                                                         \
  }

  LOAD_TILE(0)

  for (int k0 = 0; k0 < K; k0 += 32) {
    __syncthreads();  // prior frag reads done -> LDS writable
#pragma unroll
    for (int q = 0; q < AC; ++q) {
      int e = tid + q * 256;
      int m = e >> 2, kq = e & 3;
      *(uint4*)&Ash[m][kq * 8] = aPh[q];
      *(uint4*)&Asl[m][kq * 8] = aPl[q];
    }
#pragma unroll
    for (int u = 0; u < 2; ++u) {
      *(uint4*)&Wsh[wn_l][(wk8 + u) * 8] = wPh[u];
      if (TERMS == 3) *(uint4*)&Wsl[wn_l][(wk8 + u) * 8] = wPl[u];
    }
    __syncthreads();
    if (k0 + 32 < K) LOAD_TILE(k0 + 32)  // prefetch hides under MFMAs
    bf16x8 ah[WMF], al[WMF];
#pragma unroll
    for (int mi = 0; mi < WMF; ++mi) {
      ah[mi] = *(const bf16x8*)&Ash[wm + mi * 16 + fr][fg * 8];
      al[mi] = *(const bf16x8*)&Asl[wm + mi * 16 + fr][fg * 8];
    }
#pragma unroll
    for (int nj = 0; nj < 4; ++nj) {
      bf16x8 bh = *(const bf16x8*)&Wsh[wn + nj * 16 + fr][fg * 8];
#pragma unroll
      for (int mi = 0; mi < WMF; ++mi) {
        acc[mi][nj] = __builtin_amdgcn_mfma_f32_16x16x32_bf16(ah[mi], bh, acc[mi][nj], 0, 0, 0);
        acc[mi][nj] = __builtin_amdgcn_mfma_f32_16x16x32_bf16(al[mi], bh, acc[mi][nj], 0, 0, 0);
      }
      if (TERMS == 3) {
        bf16x8 bl = *(const bf16x8*)&Wsl[wn + nj * 16 + fr][fg * 8];
#pragma unroll
        for (int mi = 0; mi < WMF; ++mi)
          acc[mi][nj] = __builtin_amdgcn_mfma_f32_16x16x32_bf16(ah[mi], bl, acc[mi][nj], 0, 0, 0);
      }
    }
  }
#undef LOAD_TILE

  if (CONTIG) {
    // Contiguous epilogue (head): stage 64-row halves through LDS, then all
    // 256 threads store full-wave-contiguous 256B spans (scalar dwords).
#pragma unroll
    for (int half = 0; half < 2; ++half) {
      __syncthreads();  // frag reads (half=0) / prior stores (half=1) done
      if ((w >> 1) == half) {
#pragma unroll
        for (int mi = 0; mi < WMF; ++mi)
#pragma unroll
          for (int nj = 0; nj < 4; ++nj)
#pragma unroll
            for (int r = 0; r < 4; ++r)
              Cs[mi * 16 + fg * 4 + r][wn + nj * 16 + fr] = acc[mi][nj][r];
      }
      __syncthreads();
#pragma unroll
      for (int e4 = 0; e4 < 32; ++e4) {
        int e = tid + e4 * 256;
        int r = e >> 7, c = e & 127;
        int row = m0 + half * 64 + r;
        int col = n0 + c;
        if (col < N) {
          float vv = Cs[r][c];
          if (bias) vv += bias[col];
          C[(size_t)row * N + col] = vv;
        }
      }
    }
    return;
  }

  // scattered epilogue: D row=(lane>>4)*4+reg, col=lane&15 (m89-verified)
#pragma unroll
  for (int mi = 0; mi < WMF; ++mi) {
#pragma unroll
    for (int nj = 0; nj < 4; ++nj) {
      int col = n0 + wn + nj * 16 + fr;
      if (col < N) {
#pragma unroll
        for (int r = 0; r < 4; ++r) {
          int row = m0 + wm + mi * 16 + fg * 4 + r;
          float vv = acc[mi][nj][r];
          if (bias) vv += bias[col];
          if (addsrc) vv += addsrc[(size_t)row * N + col];
          if (RELU) vv = fmaxf(vv, 0.f);
          if (OSPLIT) {
            unsigned hb, lb;
            split_f(vv, hb, lb);
            Ch[(size_t)row * N + col] = (u16)(hb >> 16);
            Cl[(size_t)row * N + col] = (u16)(lb >> 16);
          } else {
            C[(size_t)row * N + col] = vv;
          }
        }
      }
    }
  }
}

// Reference quirk: softmax over the QUERY axis. For each (b,h,key j):
// m_j = max_{i>=j} S_ij, l_j = sum_{i>=j} exp(S_ij - m_j).  Online over i-tiles.
// q,k point into fused qkv buffer; row stride kQS.
__global__ __launch_bounds__(256) void attn_colstats_kernel(
    const float* __restrict__ q, const float* __restrict__ k,
    float* __restrict__ colm, float* __restrict__ coll) {
  __shared__ __align__(16) float ksT[64][68];  // [d][j]
  __shared__ __align__(16) float qsT[64][68];  // [d][i]
  __shared__ float red[16][64];
  __shared__ float cm[64], cl[64];
  int bh = blockIdx.x, jt = blockIdx.y;
  int b = bh / kH, h = bh % kH;
  int tid = threadIdx.x, tx = tid & 15, ty = tid >> 4;
  int j0 = jt * 64;
  size_t base = (size_t)b * kT * kQS + h * kHD;
#pragma unroll
  for (int r = 0; r < 4; ++r) {
    int idx = tid + r * 256;
    int jl = idx >> 4, dq = (idx & 15) * 4;
    float4 kv = *(const float4*)&k[base + (size_t)(j0 + jl) * kQS + dq];
    ksT[dq + 0][jl] = kv.x; ksT[dq + 1][jl] = kv.y;
    ksT[dq + 2][jl] = kv.z; ksT[dq + 3][jl] = kv.w;
  }
  if (tid < 64) { cm[tid] = -INFINITY; cl[tid] = 0.f; }
  __syncthreads();
  for (int it = jt; it < kT / 64; ++it) {
    int i0 = it * 64;
#pragma unroll
    for (int r = 0; r < 4; ++r) {
      int idx = tid + r * 256;
      int il = idx >> 4, dq = (idx & 15) * 4;
      float4 qv = *(const float4*)&q[base + (size_t)(i0 + il) * kQS + dq];
      qsT[dq + 0][il] = qv.x; qsT[dq + 1][il] = qv.y;
      qsT[dq + 2][il] = qv.z; qsT[dq + 3][il] = qv.w;
    }
    __syncthreads();
    float s[4][4] = {};
#pragma unroll 8
    for (int d = 0; d < 64; ++d) {
      float4 a4 = *(const float4*)&qsT[d][ty * 4];
      float4 b4 = *(const float4*)&ksT[d][tx * 4];
      float a[4] = {a4.x, a4.y, a4.z, a4.w};
      float bb[4] = {b4.x, b4.y, b4.z, b4.w};
#pragma unroll
      for (int i = 0; i < 4; ++i)
#pragma unroll
        for (int j = 0; j < 4; ++j) s[i][j] += a[i] * bb[j];
    }
    float tmax[4] = {-INFINITY, -INFINITY, -INFINITY, -INFINITY};
#pragma unroll
    for (int i = 0; i < 4; ++i)
#pragma unroll
      for (int j = 0; j < 4; ++j) {
        bool valid = (i0 + ty * 4 + i) >= (j0 + tx * 4 + j);
        s[i][j] = valid ? s[i][j] * kSCALE : -INFINITY;
        tmax[j] = fmaxf(tmax[j], s[i][j]);
      }
#pragma unroll
    for (int j = 0; j < 4; ++j) red[ty][tx * 4 + j] = tmax[j];
    __syncthreads();
    if (tid < 64) {
      float tm = -INFINITY;
#pragma unroll
      for (int r = 0; r < 16; ++r) tm = fmaxf(tm, red[r][tid]);
      float mo = cm[tid], mn = fmaxf(mo, tm);
      cl[tid] *= __expf(mo - mn);  // exp(-inf)=0 on first tile
      cm[tid] = mn;
    }
    __syncthreads();
    float ps[4] = {0.f, 0.f, 0.f, 0.f};
#pragma unroll
    for (int j = 0; j < 4; ++j) {
      float mj = cm[tx * 4 + j];
#pragma unroll
      for (int i = 0; i < 4; ++i) ps[j] += __expf(s[i][j] - mj);  // masked: exp(-inf)=0
    }
#pragma unroll
    for (int j = 0; j < 4; ++j) red[ty][tx * 4 + j] = ps[j];
    __syncthreads();
    if (tid < 64) {
      float a = 0.f;
#pragma unroll
      for (int r = 0; r < 16; ++r) a += red[r][tid];
      cl[tid] += a;
    }
    __syncthreads();
  }
  if (tid < 64) {
    colm[(size_t)bh * kT + j0 + tid] = cm[tid];
    coll[(size_t)bh * kT + j0 + tid] = cl[tid];
  }
}

// att[b,i,h,:] = sum_{j<=i} exp(S_ij - m_j)/l_j * v[b,j,h,:]; writes bf16 hi/lo.
__global__ __launch_bounds__(256) void attn_av_kernel(
    const float* __restrict__ q, const float* __restrict__ k,
    const float* __restrict__ v, const float* __restrict__ colm,
    const float* __restrict__ coll, u16* __restrict__ atth,
    u16* __restrict__ attl) {
  __shared__ __align__(16) float qsT[64][68];  // [d][i], loaded once
  __shared__ __align__(16) float ksT[64][68];  // [d][j]; P[j][i] aliases after use
  __shared__ __align__(16) float Vs[64][64];   // [j][d]
  __shared__ float mjs[64], ljs[64];
  float (*Ps)[68] = ksT;
  int bh = blockIdx.x, it = blockIdx.y;
  int b = bh / kH, h = bh % kH;
  int tid = threadIdx.x, tx = tid & 15, ty = tid >> 4;
  int i0 = it * 64;
  size_t base = (size_t)b * kT * kQS + h * kHD;
#pragma unroll
  for (int r = 0; r < 4; ++r) {
    int idx = tid + r * 256;
    int il = idx >> 4, dq = (idx & 15) * 4;
    float4 qv = *(const float4*)&q[base + (size_t)(i0 + il) * kQS + dq];
    qsT[dq + 0][il] = qv.x; qsT[dq + 1][il] = qv.y;
    qsT[dq + 2][il] = qv.z; qsT[dq + 3][il] = qv.w;
  }
  float acc[4][4] = {};
  for (int jt = 0; jt <= it; ++jt) {
    int j0 = jt * 64;
#pragma unroll
    for (int r = 0; r < 4; ++r) {
      int idx = tid + r * 256;
      int jl = idx >> 4, dq = (idx & 15) * 4;
      float4 kv = *(const float4*)&k[base + (size_t)(j0 + jl) * kQS + dq];
      ksT[dq + 0][jl] = kv.x; ksT[dq + 1][jl] = kv.y;
      ksT[dq + 2][jl] = kv.z; ksT[dq + 3][jl] = kv.w;
      *(float4*)&Vs[jl][dq] = *(const float4*)&v[base + (size_t)(j0 + jl) * kQS + dq];
    }
    if (tid < 64) {
      mjs[tid] = colm[(size_t)bh * kT + j0 + tid];
      ljs[tid] = 1.f / coll[(size_t)bh * kT + j0 + tid];
    }
    __syncthreads();
    float s[4][4] = {};
#pragma unroll 8
    for (int d = 0; d < 64; ++d) {
      float4 a4 = *(const float4*)&qsT[d][ty * 4];
      float4 b4 = *(const float4*)&ksT[d][tx * 4];
      float a[4] = {a4.x, a4.y, a4.z, a4.w};
      float bb[4] = {b4.x, b4.y, b4.z, b4.w};
#pragma unroll
      for (int i = 0; i < 4; ++i)
#pragma unroll
        for (int j = 0; j < 4; ++j) s[i][j] += a[i] * bb[j];
    }
    __syncthreads();  // all ksT reads done before P overwrites it
#pragma unroll
    for (int i = 0; i < 4; ++i)
#pragma unroll
      for (int j = 0; j < 4; ++j) {
        bool valid = (i0 + ty * 4 + i) >= (j0 + tx * 4 + j);
        float p = valid ? __expf(s[i][j] * kSCALE - mjs[tx * 4 + j]) * ljs[tx * 4 + j]
                        : 0.f;
        Ps[tx * 4 + j][ty * 4 + i] = p;
      }
    __syncthreads();
#pragma unroll 8
    for (int j = 0; j < 64; ++j) {
      float4 a4 = *(const float4*)&Ps[j][ty * 4];
      float4 b4 = *(const float4*)&Vs[j][tx * 4];
      float a[4] = {a4.x, a4.y, a4.z, a4.w};
      float bb[4] = {b4.x, b4.y, b4.z, b4.w};
#pragma unroll
      for (int i = 0; i < 4; ++i)
#pragma unroll
        for (int d = 0; d < 4; ++d) acc[i][d] += a[i] * bb[d];
    }
    __syncthreads();
  }
#pragma unroll
  for (int i = 0; i < 4; ++i) {
    size_t off = (size_t)(b * kT + i0 + ty * 4 + i) * kE + h * kHD + tx * 4;
    unsigned h0, l0, h1, l1, h2, l2, h3, l3;
    split_f(acc[i][0], h0, l0); split_f(acc[i][1], h1, l1);
    split_f(acc[i][2], h2, l2); split_f(acc[i][3], h3, l3);
    *(uint2*)&atth[off] = make_uint2(pk(h0, h1), pk(h2, h3));
    *(uint2*)&attl[off] = make_uint2(pk(l0, l1), pk(l2, l3));
  }
}

extern "C" void kernel_launch(void* const* d_in, const int* in_sizes, int n_in,
                              void* d_out, int out_size, void* d_ws, size_t ws_size,
                              hipStream_t stream) {
  const int* tokens    = (const int*)d_in[0];
  const float* tok_emb = (const float*)d_in[1];
  const float* pos_emb = (const float*)d_in[2];
  const float* wq      = (const float*)d_in[3];
  const float* wk      = (const float*)d_in[4];
  const float* wv      = (const float*)d_in[5];
  const float* wo      = (const float*)d_in[6];
  const float* wo_b    = (const float*)d_in[7];
  const float* ln1_g   = (const float*)d_in[8];
  const float* ln1_b   = (const float*)d_in[9];
  const float* ln2_g   = (const float*)d_in[10];
  const float* ln2_b   = (const float*)d_in[11];
  const float* ff1_w   = (const float*)d_in[12];
  const float* ff1_b   = (const float*)d_in[13];
  const float* ff2_w   = (const float*)d_in[14];
  const float* ff2_b   = (const float*)d_in[15];
  const float* lnf_g   = (const float*)d_in[16];
  const float* lnf_b   = (const float*)d_in[17];
  const float* head_w  = (const float*)d_in[18];
  const float* head_b  = (const float*)d_in[19];
  float* out = (float*)d_out;

  char* p = (char*)d_ws;
  float* x    = (float*)p;            p += (size_t)kM * kE * 4;
  float* hbuf = (float*)p;            p += (size_t)kM * kE * 4;
  u16* hh     = (u16*)p;              p += (size_t)kM * kE * 2;
  u16* hl     = (u16*)p;              p += (size_t)kM * kE * 2;
  float* qkvf = (float*)p;            p += (size_t)kM * kQS * 4;
  u16* atth   = (u16*)p;              p += (size_t)kM * kE * 2;
  u16* attl   = (u16*)p;              p += (size_t)kM * kE * 2;
  u16* ffh    = (u16*)p;              p += (size_t)kM * kFF * 2;
  u16* ffl    = (u16*)p;              p += (size_t)kM * kFF * 2;
  float* cm   = (float*)p;            p += (size_t)kB * kH * kT * 4;
  float* cl   = (float*)p;            p += (size_t)kB * kH * kT * 4;
  u16* wsw    = (u16*)p;  // weight scratch: max(28.3MB layer, 77.3MB head)
  // layer scratch layout (u16 offsets)
  u16* qkvh = wsw;                        // 768*2304
  u16* qkvl = qkvh + (size_t)kE * kQS;
  u16* woh  = qkvl + (size_t)kE * kQS;    // 768*768
  u16* wol  = woh  + (size_t)kE * kE;
  u16* f1h  = wol  + (size_t)kE * kE;     // 768*3072
  u16* f1l  = f1h  + (size_t)kE * kFF;
  u16* f2h  = f1l  + (size_t)kE * kFF;    // 3072*768
  u16* f2l  = f2h  + (size_t)kFF * kE;
  u16* headH = wsw;                       // 768*50304 (hi only, reuses scratch)

  embed_kernel<<<kM * kE / 4 / 256, 256, 0, stream>>>(tokens, tok_emb, pos_emb, x);

  // 1-D group-swizzled grids (see gemm_bf16s_kernel)
  int gQKV = (kM / 128) * (kQS / 128);   // 16*18
  int gE64 = (kM / 64) * (kE / 128);     // 32*6
  int gFF1 = (kM / 128) * (kFF / 128);   // 16*24
  int gHead = (kM / 128) * (kVP / 128);  // 16*393
  dim3 gAtt(kB * kH, kT / 64);           // 24 x 16
  dim3 cQKVO(kE / 64, kE / 64, 4);       // 12x12x4
  dim3 cFF(kFF / 64, kE / 64, 2);        // 48x12x2
  dim3 cHd(kVP / 64, kE / 64);           // 786x12

  for (int l = 0; l < kL; ++l) {
    // pre-split this layer's weights into k8-tiled bf16 (scratch reused)
    WcArgs4 a4;
    a4.src[0] = wq + (size_t)l * kE * kE; a4.dh[0] = qkvh; a4.dl[0] = qkvl; a4.colOff[0] = 0;      a4.Ndt[0] = kQS;
    a4.src[1] = wk + (size_t)l * kE * kE; a4.dh[1] = qkvh; a4.dl[1] = qkvl; a4.colOff[1] = kE;     a4.Ndt[1] = kQS;
    a4.src[2] = wv + (size_t)l * kE * kE; a4.dh[2] = qkvh; a4.dl[2] = qkvl; a4.colOff[2] = 2 * kE; a4.Ndt[2] = kQS;
    a4.src[3] = wo + (size_t)l * kE * kE; a4.dh[3] = woh;  a4.dl[3] = wol;  a4.colOff[3] = 0;      a4.Ndt[3] = kE;
    wconv_qkvo_kernel<<<cQKVO, 256, 0, stream>>>(a4);
    WcArgsFF aff;
    aff.s1 = ff1_w + (size_t)l * kE * kFF; aff.d1h = f1h; aff.d1l = f1l;
    aff.s2 = ff2_w + (size_t)l * kFF * kE; aff.d2h = f2h; aff.d2l = f2l;
    wconv_ff_kernel<<<cFF, 256, 0, stream>>>(aff);

    ln_kernel<<<kM, 256, 0, stream>>>(x, ln1_g + l * kE, ln1_b + l * kE, nullptr, hh, hl);
    gemm_bf16s_kernel<4, 3, 0, 0, 0><<<gQKV, 256, 0, stream>>>(
        hh, hl, qkvh, qkvl, nullptr, nullptr, qkvf, nullptr, nullptr, kQS, kE, kQS);
    attn_colstats_kernel<<<gAtt, 256, 0, stream>>>(qkvf, qkvf + kE, cm, cl);
    attn_av_kernel<<<gAtt, 256, 0, stream>>>(qkvf, qkvf + kE, qkvf + 2 * kE, cm, cl, atth, attl);
    gemm_bf16s_kernel<2, 3, 0, 0, 0><<<gE64, 256, 0, stream>>>(
        atth, attl, woh, wol, wo_b + l * kE, x, x, nullptr, nullptr, kE, kE, kE);
    ln_kernel<<<kM, 256, 0, stream>>>(x, ln2_g + l * kE, ln2_b + l * kE, hbuf, hh, hl);
    gemm_bf16s_kernel<4, 3, 1, 1, 0><<<gFF1, 256, 0, stream>>>(
        hh, hl, f1h, f1l, ff1_b + l * kFF, nullptr, nullptr, ffh, ffl, kFF, kE, kFF);
    gemm_bf16s_kernel<2, 3, 0, 0, 0><<<gE64, 256, 0, stream>>>(
        ffh, ffl, f2h, f2l, ff2_b + l * kE, hbuf, x, nullptr, nullptr, kE, kFF, kE);
  }
  ln_kernel<<<kM, 256, 0, stream>>>(x, lnf_g, lnf_b, nullptr, hh, hl);
  // head: W-hi only (TERMS=2): adds ~1e-3 to logits, well under tolerance
  wconv_kernel<0><<<cHd, 256, 0, stream>>>(head_w, headH, nullptr, kV, kVP, 0);
  gemm_bf16s_kernel<4, 2, 0, 0, 1><<<gHead, 256, 0, stream>>>(
      hh, hl, headH, nullptr, head_b, nullptr, out, nullptr, nullptr, kV, kE, kVP);
}

// Round 5
// 2901.432 us; speedup vs baseline: 1.5983x; 1.5983x over previous
//
#include <hip/hip_runtime.h>
#include <math.h>

namespace {
constexpr int kB = 2, kT = 1024, kE = 768, kH = 12, kL = 4, kV = 50257;
constexpr int kHD = 64;
constexpr int kM = kB * kT;   // 2048 rows
constexpr int kFF = 4 * kE;   // 3072
constexpr int kQS = 3 * kE;   // fused qkv row stride (2304)
constexpr float kEPS = 1e-3f;
constexpr float kSCALE = 0.03608439182435161f;  // 768^-0.5 (reference scales by E, not HD)
}

typedef __bf16 bf16x8 __attribute__((ext_vector_type(8)));
typedef float f32x4 __attribute__((ext_vector_type(4)));
typedef unsigned short u16;

// Pack top-16-bits (bf16 truncation) of two floats: {lo16=hi16(a), hi16=hi16(b)}.
// Bit-exact equal to ((bits(a)&0xFFFF0000)>>16) | (bits(b)&0xFFFF0000), 1 VALU op.
__device__ __forceinline__ unsigned pk2hi(float a, float b) {
#if __has_builtin(__builtin_amdgcn_perm)
  return __builtin_amdgcn_perm(__float_as_uint(b), __float_as_uint(a), 0x07060302u);
#else
  return (__float_as_uint(a) >> 16) | (__float_as_uint(b) & 0xFFFF0000u);
#endif
}
__device__ __forceinline__ float hi_f(float x) {
  return __uint_as_float(__float_as_uint(x) & 0xFFFF0000u);
}

// x[b,t,:] = tok_emb[tokens[b,t],:] + pos_emb[t,:]
__global__ __launch_bounds__(256) void embed_kernel(
    const int* __restrict__ tokens, const float* __restrict__ tok_emb,
    const float* __restrict__ pos_emb, float* __restrict__ x) {
  int gid = blockIdx.x * 256 + threadIdx.x;  // over kM*kE/4
  int m = gid / (kE / 4);
  int c = gid % (kE / 4);
  int t = m % kT;
  int tok = tokens[m];
  float4 a = ((const float4*)tok_emb)[(size_t)tok * (kE / 4) + c];
  float4 b = ((const float4*)pos_emb)[(size_t)t * (kE / 4) + c];
  ((float4*)x)[gid] = make_float4(a.x + b.x, a.y + b.y, a.z + b.z, a.w + b.w);
}

// one block (256 thr) per row of E=768: 3 elements/thread
__global__ __launch_bounds__(256) void ln_kernel(
    const float* __restrict__ x, const float* __restrict__ g,
    const float* __restrict__ bta, float* __restrict__ out) {
  __shared__ float ssum[256], ssq[256];
  int row = blockIdx.x, tid = threadIdx.x;
  const float* xr = x + (size_t)row * kE;
  float v0 = xr[tid], v1 = xr[tid + 256], v2 = xr[tid + 512];
  ssum[tid] = v0 + v1 + v2;
  ssq[tid] = v0 * v0 + v1 * v1 + v2 * v2;
  __syncthreads();
  for (int off = 128; off > 0; off >>= 1) {
    if (tid < off) { ssum[tid] += ssum[tid + off]; ssq[tid] += ssq[tid + off]; }
    __syncthreads();
  }
  float mu = ssum[0] * (1.f / kE);
  float var = ssq[0] * (1.f / kE) - mu * mu;
  float rstd = rsqrtf(var + kEPS);
  float* orow = out + (size_t)row * kE;
  orow[tid]       = (v0 - mu) * rstd * g[tid]       + bta[tid];
  orow[tid + 256] = (v1 - mu) * rstd * g[tid + 256] + bta[tid + 256];
  orow[tid + 512] = (v2 - mu) * rstd * g[tid + 512] + bta[tid + 512];
}

// Split-bf16 MFMA GEMM: C = (addsrc?) + A[M,K] @ W[K,N] + (bias?), optional ReLU.
// fp32 emulated as hi+lo bf16. TERMS=3: AhWh+AlWh+AhWl; TERMS=2: AhWh+AlWh.
// Fused-W mode (W2 != null): W is three consecutive chunks of width NW
// (wq|wk|wv); block's 128-col panel lies in exactly one chunk.
// Block: BN=128 cols, BM=WMF*32 rows, 256 thr = 4 waves 2x2; BK=32 per step.
// LDS rows 80B: all b128 reads/writes spread 8 lanes/16B-window.
// This is the R1-proven memory structure (f32 operands from HBM, in-kernel
// truncation-split via v_perm packing) — do not change store/layout behavior.
template <int WMF, int TERMS, int RELU>
__global__ __launch_bounds__(256) void gemm_mfma_kernel(
    const float* __restrict__ A, const float* __restrict__ W,
    const float* __restrict__ W2, const float* __restrict__ W3, int NW,
    const float* __restrict__ bias, const float* __restrict__ addsrc,
    float* __restrict__ C, int N, int K) {
  constexpr int BM = WMF * 32;
  __shared__ __align__(16) u16 Ahi[BM][40], Alo[BM][40];
  __shared__ __align__(16) u16 Whi[128][40], Wlo[128][40];
  const int tid = threadIdx.x;
  const int lane = tid & 63;
  const int w = tid >> 6;
  const int wm = (w >> 1) * (WMF * 16);  // wave row offset
  const int wn = (w & 1) * 64;           // wave col offset
  const int m0 = blockIdx.y * BM, n0 = blockIdx.x * 128;
  const int fr = lane & 15, fg = lane >> 4;  // frag row/col, k-group
  // keep Wlo allocated for TERMS==2 so LDS size/occupancy matches TERMS==3
  // (controlled variable vs the R1 baseline); K<0 is never true at runtime.
  if (TERMS == 2 && K < 0) *(volatile u16*)&Wlo[0][0] = 0;

  // W staging: thread owns one n-column (tid&127) x 16 k's ((tid>>7)*16 .. +15)
  const int wnl = tid & 127;
  const int wkh = tid >> 7;
  const bool wok = (n0 + wnl) < N;
  constexpr int AF4 = BM / 32;  // float4 A-loads per thread

  // fused-W resolve (uniform per block)
  const float* Wp = W;
  int ncol = n0;
  if (W2) {
    int c = n0 / NW;
    Wp = (c == 0) ? W : (c == 1) ? W2 : W3;
    ncol = n0 - c * NW;
  }
  const int wstride = W2 ? NW : N;

  f32x4 acc[WMF][4];
#pragma unroll
  for (int i = 0; i < WMF; ++i)
#pragma unroll
    for (int j = 0; j < 4; ++j) acc[i][j] = f32x4{0.f, 0.f, 0.f, 0.f};

  float4 aR[AF4];
  float wR[16];
  // prologue loads (k0 = 0)
#pragma unroll
  for (int q = 0; q < AF4; ++q) {
    int el = tid + q * 256;
    int m = el >> 3, kq = el & 7;
    aR[q] = *(const float4*)&A[(size_t)(m0 + m) * K + kq * 4];
  }
  {
    const float* wp = Wp + (size_t)(wkh * 16) * wstride + ncol + wnl;
#pragma unroll
    for (int j = 0; j < 16; ++j) wR[j] = wok ? wp[(size_t)j * wstride] : 0.f;
  }

  for (int k0 = 0; k0 < K; k0 += 32) {
    __syncthreads();  // previous frag reads done -> LDS writable
    // ---- convert + stage to LDS (perm-packed, bit-exact truncation) ----
#pragma unroll
    for (int q = 0; q < AF4; ++q) {
      int el = tid + q * 256;
      int m = el >> 3, kq = el & 7;
      float4 av = aR[q];
      float h0 = hi_f(av.x), h1 = hi_f(av.y), h2 = hi_f(av.z), h3 = hi_f(av.w);
      *(uint2*)&Ahi[m][kq * 4] = make_uint2(pk2hi(av.x, av.y), pk2hi(av.z, av.w));
      *(uint2*)&Alo[m][kq * 4] =
          make_uint2(pk2hi(av.x - h0, av.y - h1), pk2hi(av.z - h2, av.w - h3));
    }
    if (TERMS == 3) {
      float wl[16];
#pragma unroll
      for (int j = 0; j < 16; ++j) wl[j] = wR[j] - hi_f(wR[j]);
#pragma unroll
      for (int u = 0; u < 2; ++u) {
        *(uint4*)&Whi[wnl][wkh * 16 + u * 8] = make_uint4(
            pk2hi(wR[u * 8 + 0], wR[u * 8 + 1]), pk2hi(wR[u * 8 + 2], wR[u * 8 + 3]),
            pk2hi(wR[u * 8 + 4], wR[u * 8 + 5]), pk2hi(wR[u * 8 + 6], wR[u * 8 + 7]));
        *(uint4*)&Wlo[wnl][wkh * 16 + u * 8] = make_uint4(
            pk2hi(wl[u * 8 + 0], wl[u * 8 + 1]), pk2hi(wl[u * 8 + 2], wl[u * 8 + 3]),
            pk2hi(wl[u * 8 + 4], wl[u * 8 + 5]), pk2hi(wl[u * 8 + 6], wl[u * 8 + 7]));
      }
    } else {
#pragma unroll
      for (int u = 0; u < 2; ++u) {
        *(uint4*)&Whi[wnl][wkh * 16 + u * 8] = make_uint4(
            pk2hi(wR[u * 8 + 0], wR[u * 8 + 1]), pk2hi(wR[u * 8 + 2], wR[u * 8 + 3]),
            pk2hi(wR[u * 8 + 4], wR[u * 8 + 5]), pk2hi(wR[u * 8 + 6], wR[u * 8 + 7]));
      }
    }
    __syncthreads();
    // ---- prefetch next K-slab into regs (hides HBM latency under MFMAs) ----
    if (k0 + 32 < K) {
#pragma unroll
      for (int q = 0; q < AF4; ++q) {
        int el = tid + q * 256;
        int m = el >> 3, kq = el & 7;
        aR[q] = *(const float4*)&A[(size_t)(m0 + m) * K + (k0 + 32) + kq * 4];
      }
      const float* wp = Wp + (size_t)(k0 + 32 + wkh * 16) * wstride + ncol + wnl;
#pragma unroll
      for (int j = 0; j < 16; ++j) wR[j] = wok ? wp[(size_t)j * wstride] : 0.f;
    }
    // ---- frags + MFMA ----
    // A-frag lane l: row=l&15, k=8*(l>>4)+j. B-frag: col=l&15, same k order
    // (same k-permutation on both operands => result invariant to exact order).
    bf16x8 ah[WMF], al[WMF];
#pragma unroll
    for (int mi = 0; mi < WMF; ++mi) {
      ah[mi] = *(const bf16x8*)&Ahi[wm + mi * 16 + fr][fg * 8];
      al[mi] = *(const bf16x8*)&Alo[wm + mi * 16 + fr][fg * 8];
    }
#pragma unroll
    for (int nj = 0; nj < 4; ++nj) {
      bf16x8 bh = *(const bf16x8*)&Whi[wn + nj * 16 + fr][fg * 8];
#pragma unroll
      for (int mi = 0; mi < WMF; ++mi) {
        acc[mi][nj] = __builtin_amdgcn_mfma_f32_16x16x32_bf16(ah[mi], bh, acc[mi][nj], 0, 0, 0);
        acc[mi][nj] = __builtin_amdgcn_mfma_f32_16x16x32_bf16(al[mi], bh, acc[mi][nj], 0, 0, 0);
      }
      if (TERMS == 3) {
        bf16x8 bl = *(const bf16x8*)&Wlo[wn + nj * 16 + fr][fg * 8];
#pragma unroll
        for (int mi = 0; mi < WMF; ++mi)
          acc[mi][nj] = __builtin_amdgcn_mfma_f32_16x16x32_bf16(ah[mi], bl, acc[mi][nj], 0, 0, 0);
      }
    }
  }
  // ---- epilogue: D row=(lane>>4)*4+reg, col=lane&15 (m89-verified) ----
#pragma unroll
  for (int mi = 0; mi < WMF; ++mi) {
#pragma unroll
    for (int nj = 0; nj < 4; ++nj) {
      int col = n0 + wn + nj * 16 + fr;
      if (col < N) {
#pragma unroll
        for (int r = 0; r < 4; ++r) {
          int row = m0 + wm + mi * 16 + fg * 4 + r;
          float v = acc[mi][nj][r];
          if (bias) v += bias[col];
          if (addsrc) v += addsrc[(size_t)row * N + col];
          if (RELU) v = fmaxf(v, 0.f);
          C[(size_t)row * N + col] = v;
        }
      }
    }
  }
}

// Reference quirk: softmax over the QUERY axis. For each (b,h,key j):
// m_j = max_{i>=j} S_ij, l_j = sum_{i>=j} exp(S_ij - m_j).  Online over i-tiles.
// q,k row stride = qs (supports fused qkv buffer).
__global__ __launch_bounds__(256) void attn_colstats_kernel(
    const float* __restrict__ q, const float* __restrict__ k,
    float* __restrict__ colm, float* __restrict__ coll, int qs) {
  __shared__ __align__(16) float ksT[64][68];  // [d][j]
  __shared__ __align__(16) float qsT[64][68];  // [d][i]
  __shared__ float red[16][64];
  __shared__ float cm[64], cl[64];
  int bh = blockIdx.x, jt = blockIdx.y;
  int b = bh / kH, h = bh % kH;
  int tid = threadIdx.x, tx = tid & 15, ty = tid >> 4;
  int j0 = jt * 64;
  size_t base = (size_t)b * kT * qs + h * kHD;
#pragma unroll
  for (int r = 0; r < 4; ++r) {
    int idx = tid + r * 256;
    int jl = idx >> 4, dq = (idx & 15) * 4;
    float4 kv = *(const float4*)&k[base + (size_t)(j0 + jl) * qs + dq];
    ksT[dq + 0][jl] = kv.x; ksT[dq + 1][jl] = kv.y;
    ksT[dq + 2][jl] = kv.z; ksT[dq + 3][jl] = kv.w;
  }
  if (tid < 64) { cm[tid] = -INFINITY; cl[tid] = 0.f; }
  __syncthreads();
  for (int it = jt; it < kT / 64; ++it) {
    int i0 = it * 64;
#pragma unroll
    for (int r = 0; r < 4; ++r) {
      int idx = tid + r * 256;
      int il = idx >> 4, dq = (idx & 15) * 4;
      float4 qv = *(const float4*)&q[base + (size_t)(i0 + il) * qs + dq];
      qsT[dq + 0][il] = qv.x; qsT[dq + 1][il] = qv.y;
      qsT[dq + 2][il] = qv.z; qsT[dq + 3][il] = qv.w;
    }
    __syncthreads();
    float s[4][4] = {};
#pragma unroll 8
    for (int d = 0; d < 64; ++d) {
      float4 a4 = *(const float4*)&qsT[d][ty * 4];
      float4 b4 = *(const float4*)&ksT[d][tx * 4];
      float a[4] = {a4.x, a4.y, a4.z, a4.w};
      float bb[4] = {b4.x, b4.y, b4.z, b4.w};
#pragma unroll
      for (int i = 0; i < 4; ++i)
#pragma unroll
        for (int j = 0; j < 4; ++j) s[i][j] += a[i] * bb[j];
    }
    float tmax[4] = {-INFINITY, -INFINITY, -INFINITY, -INFINITY};
#pragma unroll
    for (int i = 0; i < 4; ++i)
#pragma unroll
      for (int j = 0; j < 4; ++j) {
        bool valid = (i0 + ty * 4 + i) >= (j0 + tx * 4 + j);
        s[i][j] = valid ? s[i][j] * kSCALE : -INFINITY;
        tmax[j] = fmaxf(tmax[j], s[i][j]);
      }
#pragma unroll
    for (int j = 0; j < 4; ++j) red[ty][tx * 4 + j] = tmax[j];
    __syncthreads();
    if (tid < 64) {
      float tm = -INFINITY;
#pragma unroll
      for (int r = 0; r < 16; ++r) tm = fmaxf(tm, red[r][tid]);
      float mo = cm[tid], mn = fmaxf(mo, tm);
      cl[tid] *= __expf(mo - mn);  // exp(-inf)=0 on first tile
      cm[tid] = mn;
    }
    __syncthreads();
    float ps[4] = {0.f, 0.f, 0.f, 0.f};
#pragma unroll
    for (int j = 0; j < 4; ++j) {
      float mj = cm[tx * 4 + j];
#pragma unroll
      for (int i = 0; i < 4; ++i) ps[j] += __expf(s[i][j] - mj);  // masked: exp(-inf)=0
    }
#pragma unroll
    for (int j = 0; j < 4; ++j) red[ty][tx * 4 + j] = ps[j];
    __syncthreads();
    if (tid < 64) {
      float a = 0.f;
#pragma unroll
      for (int r = 0; r < 16; ++r) a += red[r][tid];
      cl[tid] += a;
    }
    __syncthreads();
  }
  if (tid < 64) {
    colm[(size_t)bh * kT + j0 + tid] = cm[tid];
    coll[(size_t)bh * kT + j0 + tid] = cl[tid];
  }
}

// att[b,i,h,:] = sum_{j<=i} exp(S_ij - m_j)/l_j * v[b,j,h,:]
__global__ __launch_bounds__(256) void attn_av_kernel(
    const float* __restrict__ q, const float* __restrict__ k,
    const float* __restrict__ v, const float* __restrict__ colm,
    const float* __restrict__ coll, float* __restrict__ att, int qs) {
  __shared__ __align__(16) float qsT[64][68];  // [d][i], loaded once
  __shared__ __align__(16) float ksT[64][68];  // [d][j]; P[j][i] aliases this after use
  __shared__ __align__(16) float Vs[64][64];   // [j][d]
  __shared__ float mjs[64], ljs[64];
  float (*Ps)[68] = ksT;
  int bh = blockIdx.x, it = blockIdx.y;
  int b = bh / kH, h = bh % kH;
  int tid = threadIdx.x, tx = tid & 15, ty = tid >> 4;
  int i0 = it * 64;
  size_t base = (size_t)b * kT * qs + h * kHD;
#pragma unroll
  for (int r = 0; r < 4; ++r) {
    int idx = tid + r * 256;
    int il = idx >> 4, dq = (idx & 15) * 4;
    float4 qv = *(const float4*)&q[base + (size_t)(i0 + il) * qs + dq];
    qsT[dq + 0][il] = qv.x; qsT[dq + 1][il] = qv.y;
    qsT[dq + 2][il] = qv.z; qsT[dq + 3][il] = qv.w;
  }
  float acc[4][4] = {};
  for (int jt = 0; jt <= it; ++jt) {
    int j0 = jt * 64;
#pragma unroll
    for (int r = 0; r < 4; ++r) {
      int idx = tid + r * 256;
      int jl = idx >> 4, dq = (idx & 15) * 4;
      float4 kv = *(const float4*)&k[base + (size_t)(j0 + jl) * qs + dq];
      ksT[dq + 0][jl] = kv.x; ksT[dq + 1][jl] = kv.y;
      ksT[dq + 2][jl] = kv.z; ksT[dq + 3][jl] = kv.w;
      *(float4*)&Vs[jl][dq] = *(const float4*)&v[base + (size_t)(j0 + jl) * qs + dq];
    }
    if (tid < 64) {
      mjs[tid] = colm[(size_t)bh * kT + j0 + tid];
      ljs[tid] = 1.f / coll[(size_t)bh * kT + j0 + tid];
    }
    __syncthreads();
    float s[4][4] = {};
#pragma unroll 8
    for (int d = 0; d < 64; ++d) {
      float4 a4 = *(const float4*)&qsT[d][ty * 4];
      float4 b4 = *(const float4*)&ksT[d][tx * 4];
      float a[4] = {a4.x, a4.y, a4.z, a4.w};
      float bb[4] = {b4.x, b4.y, b4.z, b4.w};
#pragma unroll
      for (int i = 0; i < 4; ++i)
#pragma unroll
        for (int j = 0; j < 4; ++j) s[i][j] += a[i] * bb[j];
    }
    __syncthreads();  // all ksT reads done before P overwrites it
#pragma unroll
    for (int i = 0; i < 4; ++i)
#pragma unroll
      for (int j = 0; j < 4; ++j) {
        bool valid = (i0 + ty * 4 + i) >= (j0 + tx * 4 + j);
        float p = valid ? __expf(s[i][j] * kSCALE - mjs[tx * 4 + j]) * ljs[tx * 4 + j]
                        : 0.f;
        Ps[tx * 4 + j][ty * 4 + i] = p;
      }
    __syncthreads();
#pragma unroll 8
    for (int j = 0; j < 64; ++j) {
      float4 a4 = *(const float4*)&Ps[j][ty * 4];
      float4 b4 = *(const float4*)&Vs[j][tx * 4];
      float a[4] = {a4.x, a4.y, a4.z, a4.w};
      float bb[4] = {b4.x, b4.y, b4.z, b4.w};
#pragma unroll
      for (int i = 0; i < 4; ++i)
#pragma unroll
        for (int d = 0; d < 4; ++d) acc[i][d] += a[i] * bb[d];
    }
    __syncthreads();
  }
#pragma unroll
  for (int i = 0; i < 4; ++i) {
    size_t off = (size_t)(b * kT + i0 + ty * 4 + i) * kE + h * kHD + tx * 4;
    *(float4*)&att[off] = make_float4(acc[i][0], acc[i][1], acc[i][2], acc[i][3]);
  }
}

extern "C" void kernel_launch(void* const* d_in, const int* in_sizes, int n_in,
                              void* d_out, int out_size, void* d_ws, size_t ws_size,
                              hipStream_t stream) {
  const int* tokens    = (const int*)d_in[0];
  const float* tok_emb = (const float*)d_in[1];
  const float* pos_emb = (const float*)d_in[2];
  const float* wq      = (const float*)d_in[3];
  const float* wk      = (const float*)d_in[4];
  const float* wv      = (const float*)d_in[5];
  const float* wo      = (const float*)d_in[6];
  const float* wo_b    = (const float*)d_in[7];
  const float* ln1_g   = (const float*)d_in[8];
  const float* ln1_b   = (const float*)d_in[9];
  const float* ln2_g   = (const float*)d_in[10];
  const float* ln2_b   = (const float*)d_in[11];
  const float* ff1_w   = (const float*)d_in[12];
  const float* ff1_b   = (const float*)d_in[13];
  const float* ff2_w   = (const float*)d_in[14];
  const float* ff2_b   = (const float*)d_in[15];
  const float* lnf_g   = (const float*)d_in[16];
  const float* lnf_b   = (const float*)d_in[17];
  const float* head_w  = (const float*)d_in[18];
  const float* head_b  = (const float*)d_in[19];
  float* out = (float*)d_out;

  float* ws   = (float*)d_ws;
  float* x    = ws;                          // [M,E]
  float* hbuf = x    + (size_t)kM * kE;      // [M,E]
  float* qkvf = hbuf + (size_t)kM * kE;      // [M,3E] fused q|k|v
  float* attb = qkvf + (size_t)kM * kQS;     // [M,E]
  float* ffb  = attb + (size_t)kM * kE;      // [M,4E]
  float* cm   = ffb  + (size_t)kM * kFF;     // [B*H*T]
  float* cl   = cm   + (size_t)kB * kH * kT; // [B*H*T]

  embed_kernel<<<kM * kE / 4 / 256, 256, 0, stream>>>(tokens, tok_emb, pos_emb, x);

  dim3 gQKV(kQS / 128, kM / 128);          // (18, 16) WMF=4, fused W
  dim3 gE(kE / 128, kM / 64);              // (6, 32)  WMF=2
  dim3 gFF1(kFF / 128, kM / 128);          // (24, 16) WMF=4
  dim3 gHead((kV + 127) / 128, kM / 128);  // (393, 16) WMF=4 TERMS=2
  dim3 gAtt(kB * kH, kT / 64);             // 24 x 16
  for (int l = 0; l < kL; ++l) {
    ln_kernel<<<kM, 256, 0, stream>>>(x, ln1_g + l * kE, ln1_b + l * kE, hbuf);
    gemm_mfma_kernel<4, 3, 0><<<gQKV, 256, 0, stream>>>(
        hbuf, wq + (size_t)l * kE * kE, wk + (size_t)l * kE * kE,
        wv + (size_t)l * kE * kE, kE, nullptr, nullptr, qkvf, kQS, kE);
    attn_colstats_kernel<<<gAtt, 256, 0, stream>>>(qkvf, qkvf + kE, cm, cl, kQS);
    attn_av_kernel<<<gAtt, 256, 0, stream>>>(qkvf, qkvf + kE, qkvf + 2 * kE, cm, cl, attb, kQS);
    gemm_mfma_kernel<2, 3, 0><<<gE, 256, 0, stream>>>(
        attb, wo + (size_t)l * kE * kE, nullptr, nullptr, 0,
        wo_b + l * kE, x, x, kE, kE);
    ln_kernel<<<kM, 256, 0, stream>>>(x, ln2_g + l * kE, ln2_b + l * kE, hbuf);
    gemm_mfma_kernel<4, 3, 1><<<gFF1, 256, 0, stream>>>(
        hbuf, ff1_w + (size_t)l * kE * kFF, nullptr, nullptr, 0,
        ff1_b + l * kFF, nullptr, ffb, kFF, kE);
    gemm_mfma_kernel<2, 3, 0><<<gE, 256, 0, stream>>>(
        ffb, ff2_w + (size_t)l * kFF * kE, nullptr, nullptr, 0,
        ff2_b + l * kE, hbuf, x, kE, kFF);
  }
  ln_kernel<<<kM, 256, 0, stream>>>(x, lnf_g, lnf_b, hbuf);
  // head: TERMS=2 (drop Ah*Wl term; ~1e-3 logit delta, validated R2-R4)
  gemm_mfma_kernel<4, 2, 0><<<gHead, 256, 0, stream>>>(
      hbuf, head_w, nullptr, nullptr, 0, head_b, nullptr, out, kV, kE);
}